// Round 1
// baseline (170.773 us; speedup 1.0000x reference)
//
#include <hip/hip_runtime.h>
#include <math.h>

#define EPS 1e-8f
#define LAMBDA 1e-3f

__device__ __forceinline__ float redsum32(float v) {
  #pragma unroll
  for (int off = 16; off >= 1; off >>= 1) v += __shfl_xor(v, off, 32);
  return v;
}
__device__ __forceinline__ float redmax32(float v) {
  #pragma unroll
  for (int off = 16; off >= 1; off >>= 1) v = fmaxf(v, __shfl_xor(v, off, 32));
  return v;
}

// One block per output row n (508 rows). 256 threads = 8 chunks x 32 c.
// Thread (chunk,c) owns output capsule c for B in [chunk*36, chunk*36+36).
__launch_bounds__(256, 2)
__global__ void convcaps_kernel(const float* __restrict__ x,
                                const float* __restrict__ wgl,
                                const float* __restrict__ beta_u,
                                const float* __restrict__ beta_a,
                                float* __restrict__ out) {
  __shared__ float xr[288][16];     // pose patches, 18 KB
  __shared__ float a_sh[288];       // activations
  __shared__ float red[33][256];    // chunk-reduction scratch (A1[16],A2[16],S)
  __shared__ float mu_l[32][16];
  __shared__ float i2s_l[32][16];   // 1/(2*sigma)
  __shared__ float hl_l[32][16];    // 0.5*ln(sigma)
  __shared__ float S_l[32];         // r_sum per c
  __shared__ float aout_l[32];
  __shared__ float lnao_l[32];

  const int tid = threadIdx.x;
  const int n = blockIdx.x;
  const int c = tid & 31;
  const int chunk = tid >> 5;

  // ---- stage the 9 source rows: xr[B][s], a_sh[B] ----
  for (int t = 0; t < 9; ++t) {
    int g = 9 * n + t;
    int bg = g / 2286;              // 2286 = 9*254
    int ki = (g % 2286) / 762;      // 762 = 3*254
    int owp = g % 254;              // 762,2286 are multiples of 254
    const float* src = x + (size_t)((bg * 256 + ki + owp) * 4) * 544;
    for (int e = tid; e < 544; e += 256) {
      float val = src[e];
      if (e < 512) xr[t * 32 + (e >> 4)][e & 15] = val;
      else         a_sh[t * 32 + (e - 512)] = val;
    }
  }
  __syncthreads();

  float A1[16], A2[16], Ssum;
  float mu[16], i2s[16];
  float Hl = 0.f, lnao = 0.f;

  const size_t rbase = 276352;  // 2*254*544, start of r output

  for (int pass = 0; pass < 3; ++pass) {
    #pragma unroll
    for (int s = 0; s < 16; ++s) { A1[s] = 0.f; A2[s] = 0.f; }
    Ssum = 0.f;
    if (pass > 0) {
      Hl = 0.f;
      #pragma unroll
      for (int s = 0; s < 16; ++s) {
        mu[s] = mu_l[c][s];
        i2s[s] = i2s_l[c][s];
        Hl += hl_l[c][s];
      }
      lnao = lnao_l[c];
    }

    for (int i = 0; i < 36; ++i) {
      int B = chunk * 36 + i;
      const float4* wp = reinterpret_cast<const float4*>(wgl + ((size_t)(B * 32 + c)) * 16);
      float4 w0 = wp[0], w1 = wp[1], w2 = wp[2], w3 = wp[3];
      float v[16];
      #pragma unroll
      for (int r4 = 0; r4 < 4; ++r4) {
        float x0 = xr[B][r4 * 4 + 0], x1 = xr[B][r4 * 4 + 1];
        float x2 = xr[B][r4 * 4 + 2], x3 = xr[B][r4 * 4 + 3];
        v[r4 * 4 + 0] = fmaf(x3, w3.x, fmaf(x2, w2.x, fmaf(x1, w1.x, x0 * w0.x)));
        v[r4 * 4 + 1] = fmaf(x3, w3.y, fmaf(x2, w2.y, fmaf(x1, w1.y, x0 * w0.y)));
        v[r4 * 4 + 2] = fmaf(x3, w3.z, fmaf(x2, w2.z, fmaf(x1, w1.z, x0 * w0.z)));
        v[r4 * 4 + 3] = fmaf(x3, w3.w, fmaf(x2, w2.w, fmaf(x1, w1.w, x0 * w0.w)));
      }
      float aB = a_sh[B];
      float rt;
      if (pass == 0) {
        rt = aB * 0.03125f;                      // r0 = 1/32, times a_in
      } else {
        // e-step: ln_ap (dropping softmax-invariant -8*ln(2pi))
        float acc = 0.f;
        #pragma unroll
        for (int s = 0; s < 16; ++s) {
          float d = v[s] - mu[s];
          acc = fmaf(d * d, i2s[s], acc);
        }
        float lnap = lnao - acc - Hl;
        float mx = redmax32(lnap);
        float e = __expf(lnap - mx);
        float se = redsum32(e);
        float r2 = e / se;                       // softmax over c
        if (pass == 2) out[rbase + ((size_t)n * 288 + B) * 32 + c] = r2;
        rt = r2 * aB;
      }
      float su = redsum32(rt);                   // sum over c of r*a
      float wgt = rt / (su + EPS);               // r-tilde (c-normalized)
      #pragma unroll
      for (int s = 0; s < 16; ++s) {
        float p = wgt * v[s];
        A1[s] += p;                              // sum r~ * v
        A2[s] = fmaf(p, v[s], A2[s]);            // sum r~ * v^2
      }
      Ssum += wgt;                               // partial r_sum
    }

    // ---- reduce across 8 chunks ----
    #pragma unroll
    for (int s = 0; s < 16; ++s) { red[s][tid] = A1[s]; red[16 + s][tid] = A2[s]; }
    red[32][tid] = Ssum;
    __syncthreads();

    // finalize mu / sigma; tasks (c2, s) mapped so lane == c2 (bank-conflict-free)
    #pragma unroll
    for (int rep = 0; rep < 2; ++rep) {
      int s = (tid >> 5) + rep * 8;
      int c2 = tid & 31;
      float a1 = 0.f, a2 = 0.f, ss = 0.f;
      #pragma unroll
      for (int ch = 0; ch < 8; ++ch) {
        int col = ch * 32 + c2;
        a1 += red[s][col];
        a2 += red[16 + s][col];
        ss += red[32][col];
      }
      float inv = 1.0f / (ss + EPS);
      float m = a1 * inv;                        // mu
      float Sc = ss * inv;                       // sum of coeff
      float sg = fmaf(-m * m, 2.0f - Sc, a2 * inv) + EPS;  // sigma_sq
      mu_l[c2][s] = m;
      i2s_l[c2][s] = 0.5f / sg;
      hl_l[c2][s] = 0.5f * __logf(sg);
      if (s == 0) S_l[c2] = ss;
    }
    __syncthreads();

    // a_out per c
    if (tid < 32) {
      float sh = 0.f;
      #pragma unroll
      for (int s = 0; s < 16; ++s) sh += hl_l[tid][s];
      float cost = fmaf(beta_u[tid], 16.0f, sh) * S_l[tid];
      float z = LAMBDA * (beta_a[tid] - cost);
      float ao = 1.0f / (1.0f + __expf(-z));
      aout_l[tid] = ao;
      lnao_l[tid] = __logf(ao);
    }
    __syncthreads();
  }

  // ---- outputs: row n = [mu (512) | a_out (32)] ----
  #pragma unroll
  for (int rep = 0; rep < 2; ++rep) {
    int s = (tid >> 5) + rep * 8;
    int c2 = tid & 31;
    out[(size_t)n * 544 + c2 * 16 + s] = mu_l[c2][s];
  }
  if (tid < 32) out[(size_t)n * 544 + 512 + tid] = aout_l[tid];
}

extern "C" void kernel_launch(void* const* d_in, const int* in_sizes, int n_in,
                              void* d_out, int out_size, void* d_ws, size_t ws_size,
                              hipStream_t stream) {
  const float* x  = (const float*)d_in[0];
  const float* w  = (const float*)d_in[1];
  const float* bu = (const float*)d_in[2];
  const float* ba = (const float*)d_in[3];
  float* out = (float*)d_out;
  convcaps_kernel<<<dim3(508), dim3(256), 0, stream>>>(x, w, bu, ba, out);
}

// Round 2
// 141.337 us; speedup vs baseline: 1.2083x; 1.2083x over previous
//
#include <hip/hip_runtime.h>
#include <math.h>

#define EPS 1e-8f
#define LAMBDA 1e-3f

__device__ __forceinline__ float redsum32(float v) {
  #pragma unroll
  for (int off = 16; off >= 1; off >>= 1) v += __shfl_xor(v, off, 32);
  return v;
}
__device__ __forceinline__ float redmax32(float v) {
  #pragma unroll
  for (int off = 16; off >= 1; off >>= 1) v = fmaxf(v, __shfl_xor(v, off, 32));
  return v;
}

// One block per output row n (508 rows). 512 threads = 16 chunks x 32 c.
// Thread (chunk,c) owns output capsule c for B in [chunk*18, chunk*18+18).
// su = sum_c(r*a) == a exactly (softmax sums to 1), so the c-normalization
// is folded into af = a/(a+EPS) at staging -> one fewer shuffle tree.
__launch_bounds__(512, 4)
__global__ void convcaps_kernel(const float* __restrict__ x,
                                const float* __restrict__ wgl,
                                const float* __restrict__ beta_u,
                                const float* __restrict__ beta_a,
                                float* __restrict__ out) {
  __shared__ float xr[288][16];       // pose patches, 18 KB
  __shared__ float a_sh[288];         // a/(a+EPS)
  __shared__ float red[33][256];      // per-wave partials (A1[16],A2[16],S)
  __shared__ float mu_l[32][17];      // +1 pad: stride 17 coprime 32
  __shared__ float i2s_l[32][17];     // 1/(2*sigma)
  __shared__ float hl_l[32][17];      // 0.5*ln(sigma)
  __shared__ float S_l[32];
  __shared__ float aout_l[32];
  __shared__ float lnao_l[32];

  const int tid = threadIdx.x;
  const int n = blockIdx.x;
  const int c = tid & 31;
  const int chunk = tid >> 5;         // 0..15

  // ---- stage 9 source rows (float4): xr[B][s], a_sh[B] ----
  for (int idx = tid; idx < 1224; idx += 512) {   // 9 * 136 float4
    int t = idx / 136;
    int e4 = idx - t * 136;
    int g = 9 * n + t;
    int bg = g / 2286;                 // 2286 = 9*254
    int ki = (g % 2286) / 762;         // 762 = 3*254
    int owp = g % 254;
    const float4* src = reinterpret_cast<const float4*>(x) +
                        (size_t)((bg * 256 + ki + owp) * 4) * 136;
    float4 val = src[e4];
    if (e4 < 128) reinterpret_cast<float4*>(&xr[0][0])[t * 128 + e4] = val;
    else          reinterpret_cast<float4*>(a_sh)[t * 8 + (e4 - 128)] = val;
  }
  __syncthreads();
  for (int e = tid; e < 288; e += 512) { float a = a_sh[e]; a_sh[e] = a / (a + EPS); }
  __syncthreads();

  float A1[16], A2[16], Ssum;
  float mu[16], i2s[16];
  const size_t rbase = 276352;         // 2*254*544

  for (int pass = 0; pass < 3; ++pass) {
    #pragma unroll
    for (int s = 0; s < 16; ++s) { A1[s] = 0.f; A2[s] = 0.f; }
    Ssum = 0.f;
    float bias = 0.f;
    if (pass > 0) {
      float Hl = 0.f;
      #pragma unroll
      for (int s = 0; s < 16; ++s) {
        mu[s] = mu_l[c][s];
        i2s[s] = i2s_l[c][s];
        Hl += hl_l[c][s];
      }
      bias = lnao_l[c] - Hl;
    }

    for (int i = 0; i < 18; ++i) {
      int B = chunk * 18 + i;
      const float4* wp = reinterpret_cast<const float4*>(wgl + ((size_t)(B * 32 + c)) * 16);
      float4 w0 = wp[0], w1 = wp[1], w2 = wp[2], w3 = wp[3];
      const float4* xp = reinterpret_cast<const float4*>(&xr[B][0]);
      float4 xv0 = xp[0], xv1 = xp[1], xv2 = xp[2], xv3 = xp[3];
      float v[16];
      {
        float x0 = xv0.x, x1 = xv0.y, x2 = xv0.z, x3 = xv0.w;
        v[0] = fmaf(x3, w3.x, fmaf(x2, w2.x, fmaf(x1, w1.x, x0 * w0.x)));
        v[1] = fmaf(x3, w3.y, fmaf(x2, w2.y, fmaf(x1, w1.y, x0 * w0.y)));
        v[2] = fmaf(x3, w3.z, fmaf(x2, w2.z, fmaf(x1, w1.z, x0 * w0.z)));
        v[3] = fmaf(x3, w3.w, fmaf(x2, w2.w, fmaf(x1, w1.w, x0 * w0.w)));
      }
      {
        float x0 = xv1.x, x1 = xv1.y, x2 = xv1.z, x3 = xv1.w;
        v[4] = fmaf(x3, w3.x, fmaf(x2, w2.x, fmaf(x1, w1.x, x0 * w0.x)));
        v[5] = fmaf(x3, w3.y, fmaf(x2, w2.y, fmaf(x1, w1.y, x0 * w0.y)));
        v[6] = fmaf(x3, w3.z, fmaf(x2, w2.z, fmaf(x1, w1.z, x0 * w0.z)));
        v[7] = fmaf(x3, w3.w, fmaf(x2, w2.w, fmaf(x1, w1.w, x0 * w0.w)));
      }
      {
        float x0 = xv2.x, x1 = xv2.y, x2 = xv2.z, x3 = xv2.w;
        v[8]  = fmaf(x3, w3.x, fmaf(x2, w2.x, fmaf(x1, w1.x, x0 * w0.x)));
        v[9]  = fmaf(x3, w3.y, fmaf(x2, w2.y, fmaf(x1, w1.y, x0 * w0.y)));
        v[10] = fmaf(x3, w3.z, fmaf(x2, w2.z, fmaf(x1, w1.z, x0 * w0.z)));
        v[11] = fmaf(x3, w3.w, fmaf(x2, w2.w, fmaf(x1, w1.w, x0 * w0.w)));
      }
      {
        float x0 = xv3.x, x1 = xv3.y, x2 = xv3.z, x3 = xv3.w;
        v[12] = fmaf(x3, w3.x, fmaf(x2, w2.x, fmaf(x1, w1.x, x0 * w0.x)));
        v[13] = fmaf(x3, w3.y, fmaf(x2, w2.y, fmaf(x1, w1.y, x0 * w0.y)));
        v[14] = fmaf(x3, w3.z, fmaf(x2, w2.z, fmaf(x1, w1.z, x0 * w0.z)));
        v[15] = fmaf(x3, w3.w, fmaf(x2, w2.w, fmaf(x1, w1.w, x0 * w0.w)));
      }

      float af = a_sh[B];
      float wgt;
      if (pass == 0) {
        wgt = af * 0.03125f;
      } else {
        float acc = 0.f;
        #pragma unroll
        for (int s = 0; s < 16; ++s) {
          float d = v[s] - mu[s];
          acc = fmaf(d * d, i2s[s], acc);
        }
        float lnap = bias - acc;
        float mx = redmax32(lnap);
        float e = __expf(lnap - mx);
        float se = redsum32(e);
        float r2 = e * __builtin_amdgcn_rcpf(se);
        if (pass == 2) out[rbase + ((size_t)n * 288 + B) * 32 + c] = r2;
        wgt = r2 * af;
      }
      #pragma unroll
      for (int s = 0; s < 16; ++s) {
        float p = wgt * v[s];
        A1[s] += p;
        A2[s] = fmaf(p, v[s], A2[s]);
      }
      Ssum += wgt;
    }

    // ---- pre-reduce across the two wave halves, then LDS across 8 waves ----
    #pragma unroll
    for (int s = 0; s < 16; ++s) {
      A1[s] += __shfl_xor(A1[s], 32, 64);
      A2[s] += __shfl_xor(A2[s], 32, 64);
    }
    Ssum += __shfl_xor(Ssum, 32, 64);
    if ((tid & 63) < 32) {
      int col = (tid >> 6) * 32 + c;
      #pragma unroll
      for (int s = 0; s < 16; ++s) { red[s][col] = A1[s]; red[16 + s][col] = A2[s]; }
      red[32][col] = Ssum;
    }
    __syncthreads();

    // finalize mu/sigma: exactly one (c2,s) task per thread
    {
      int s = tid >> 5;
      int c2 = tid & 31;
      float a1 = 0.f, a2 = 0.f, ss = 0.f;
      #pragma unroll
      for (int ch = 0; ch < 8; ++ch) {
        int col = ch * 32 + c2;
        a1 += red[s][col];
        a2 += red[16 + s][col];
        ss += red[32][col];
      }
      float inv = __builtin_amdgcn_rcpf(ss + EPS);
      float m = a1 * inv;
      float Sc = ss * inv;
      float sg = fmaf(-m * m, 2.0f - Sc, a2 * inv) + EPS;   // sigma_sq
      mu_l[c2][s] = m;
      i2s_l[c2][s] = 0.5f * __builtin_amdgcn_rcpf(sg);
      hl_l[c2][s] = 0.5f * __logf(sg);
      if (s == 0) S_l[c2] = ss;
    }
    __syncthreads();

    if (tid < 32) {
      float sh = 0.f;
      #pragma unroll
      for (int s = 0; s < 16; ++s) sh += hl_l[tid][s];
      float cost = fmaf(beta_u[tid], 16.0f, sh) * S_l[tid];
      float z = LAMBDA * (beta_a[tid] - cost);
      float ao = __builtin_amdgcn_rcpf(1.0f + __expf(-z));
      aout_l[tid] = ao;
      lnao_l[tid] = __logf(ao);
    }
    __syncthreads();
  }

  // ---- outputs: row n = [mu (512) | a_out (32)], coalesced ----
  {
    int c2 = tid >> 4;
    int s = tid & 15;
    out[(size_t)n * 544 + tid] = mu_l[c2][s];
  }
  if (tid < 32) out[(size_t)n * 544 + 512 + tid] = aout_l[tid];
}

extern "C" void kernel_launch(void* const* d_in, const int* in_sizes, int n_in,
                              void* d_out, int out_size, void* d_ws, size_t ws_size,
                              hipStream_t stream) {
  const float* x  = (const float*)d_in[0];
  const float* w  = (const float*)d_in[1];
  const float* bu = (const float*)d_in[2];
  const float* ba = (const float*)d_in[3];
  float* out = (float*)d_out;
  convcaps_kernel<<<dim3(508), dim3(512), 0, stream>>>(x, w, bu, ba, out);
}